// Round 8
// baseline (708.954 us; speedup 1.0000x reference)
//
#include <hip/hip_runtime.h>

// Balanced sinkhorn, persistent kernel, round 13.
// R12 post-mortem: "per-element" polling is narrow per-THREAD but machine-
// wide it's still a 65536-element flood until the last publisher lands
// (same as R7). Consolidated R5-R12 law: DETECTION must be minimal-width
// tag lines; DATA must move exactly once, after detection. R5 (family best,
// 9.3us/phase) obeys this everywhere except its consumer hop; R12 violated
// it in the gather. R13 makes BOTH hops tag-gated with one-shot data:
//   leg1: publish 2KB row (coalesced) -> drain+barrier -> flag1[bid]=ph
//         (monotonic u32 tag: no ABA, no sentinels, no NaN init)
//   leg2: 16 reducers: thread t polls flag1[t] (256 tags on 16 lines,
//         self-narrowing) -> barrier -> ONE-SHOT strided gather ->
//         deterministic 16x16 LDS fold (ascending b order)
//   leg3: replica slice writes (x16) -> drain+barrier -> flag2[red]=ph
//         (16 tags in ONE 64B line)
//   leg4: consumers poll the single flag2 line (t<16) -> barrier ->
//         ONE-SHOT coalesced 2KB read of replica row
// P/res reuse at parity-2 without sentinels: publisher writes P(ph+2) only
// after consuming res(ph+1), which requires all flag1>=ph+1, which requires
// every block consumed res(ph) (R5-validated double-gating).
// Phase math / LDS tiles / replicated optimizer identical to R3-R12
// (validated, absmax 2.4e-4; summation order identical to R12).

namespace {

constexpr int KDIM = 256;
constexpr int NBLK = 256;   // 1 block/CU, all co-resident (LDS-forced)
constexpr int ROWS = 64;    // rows per block
constexpr int NRED = 16;    // reducer blocks
constexpr int NREP = 16;    // result replicas
constexpr float L2E20 = 28.853900817779268f;  // 20 * log2(e)

// ws layout (doubles):
//   P  [2][256 blk][256 k]   131072 dbl  publish rows (parity-2, tag-gated)
//   res[2][16 rep][256 k]      8192 dbl  result rows (parity-2, tag-gated)
//   flag1[256] u32 + flag2[16] u32      publisher / result tags
constexpr size_t RES_OFF = 2ull * NBLK * KDIM;          // 131072
constexpr size_t FLG_OFF = RES_OFF + 2ull * NREP * KDIM; // 139264
constexpr size_t WS_DBL  = FLG_OFF + 64;                 // flags in 512 B

__device__ __forceinline__ double fast_exp_d(double x) {
  const double LOG2E  = 1.4426950408889634074;
  const double LN2_HI = 6.93147180369123816490e-01;
  const double LN2_LO = 1.90821492927058770002e-10;
  double n = rint(x * LOG2E);
  double t = fma(-n, LN2_HI, x);
  t = fma(-n, LN2_LO, t);
  double p = 2.4801587301587302e-05;
  p = fma(p, t, 1.9841269841269841e-04);
  p = fma(p, t, 1.3888888888888889e-03);
  p = fma(p, t, 8.3333333333333333e-03);
  p = fma(p, t, 4.1666666666666664e-02);
  p = fma(p, t, 1.6666666666666666e-01);
  p = fma(p, t, 0.5);
  p = fma(p, t, 1.0);
  p = fma(p, t, 1.0);
  long long ni = (long long)n;
  double s = __longlong_as_double((unsigned long long)(ni + 1023LL) << 52);
  return p * s;
}

__device__ __forceinline__ double wave_sum_d(double v) {
#pragma unroll
  for (int o = 32; o > 0; o >>= 1) v += __shfl_down(v, o);
  return v;
}
__device__ __forceinline__ double wave_max_d(double v) {
#pragma unroll
  for (int o = 32; o > 0; o >>= 1) v = fmax(v, __shfl_down(v, o));
  return v;
}

__device__ __forceinline__ double pload(const double* p) {
  return __hip_atomic_load(p, __ATOMIC_RELAXED, __HIP_MEMORY_SCOPE_AGENT);
}
__device__ __forceinline__ void pstore(double* p, double v) {
  __hip_atomic_store(p, v, __ATOMIC_RELAXED, __HIP_MEMORY_SCOPE_AGENT);
}
__device__ __forceinline__ unsigned aload(const unsigned* p) {
  return __hip_atomic_load(p, __ATOMIC_RELAXED, __HIP_MEMORY_SCOPE_AGENT);
}
__device__ __forceinline__ void astore(unsigned* p, unsigned v) {
  __hip_atomic_store(p, v, __ATOMIC_RELAXED, __HIP_MEMORY_SCOPE_AGENT);
}

}  // namespace

// ---------------------------------------------------------------------------
__global__ __launch_bounds__(256) void kInitWS(double* __restrict__ ws) {
  size_t gid = (size_t)blockIdx.x * 256 + threadIdx.x;
  unsigned* fl = (unsigned*)(ws + FLG_OFF);
  if (gid < 272 + 16) fl[gid] = 0u;  // flag1[256] + flag2[16] (+ pad)
}

// ---------------------------------------------------------------------------
__global__ __launch_bounds__(256, 1) void sink_main(
    const float* __restrict__ feat, const float* __restrict__ w_in,
    float* __restrict__ out, double* __restrict__ ws) {
  __shared__ float  Et[ROWS * KDIM];   // 64 KB
  __shared__ float  Ft[ROWS * KDIM];   // 64 KB
  __shared__ double alpha[KDIM];
  __shared__ double tmp1[KDIM];        // reducer fold stage 1
  __shared__ double sfin[16];          // reducer fold stage 2
  __shared__ double v1s[ROWS], v2s[ROWS], v3s[ROWS];
  __shared__ double grow[ROWS], wrow[ROWS], sbr[ROWS];
  __shared__ float  mrow[ROWS];
  __shared__ double sred[8];

  const int t = threadIdx.x, bid = blockIdx.x;
  const int wv = t >> 6, lane = t & 63;
  const int b0 = bid * ROWS;

  double* P     = ws;
  double* res   = ws + RES_OFF;
  unsigned* flag1 = (unsigned*)(ws + FLG_OFF);
  unsigned* flag2 = flag1 + 256;

  auto blk_sum = [&](double v) -> double {
    v = wave_sum_d(v);
    __syncthreads();
    if (lane == 0) sred[wv] = v;
    __syncthreads();
    return sred[0] + sred[1] + sred[2] + sred[3];
  };
  auto blk_max = [&](double v) -> double {
    v = wave_max_d(v);
    __syncthreads();
    if (lane == 0) sred[wv + 4] = v;
    __syncthreads();
    return fmax(fmax(sred[4], sred[5]), fmax(sred[6], sred[7]));
  };

  // ---- allreduce over blocks: thread t contributes pa for k=t,
  // returns the 256-block sum for k=t (identical in every block).
  auto allreduce = [&](unsigned ph, double pa) -> double {
    const int par = (int)(ph & 1);
    double* Pp = P + (size_t)par * NBLK * KDIM;
    double* Rp = res + (size_t)par * NREP * KDIM;
    // leg1: publish own row (coalesced, one-shot), drain, tag
    pstore(Pp + (size_t)bid * KDIM + t, pa);
    asm volatile("s_waitcnt vmcnt(0)" ::: "memory");
    __syncthreads();
    if (t == 0) astore(flag1 + bid, ph);
    if (bid < NRED) {
      // leg2: narrow tag poll (256 tags / 16 lines, self-narrowing)
      {
        unsigned v = aload(flag1 + t);
        while (v < ph) {
          __builtin_amdgcn_s_sleep(1);
          v = aload(flag1 + t);
        }
      }
      __syncthreads();
      // one-shot strided gather: reducer bid owns k in [16bid, 16bid+16);
      // thread (seg=t>>4, kl=t&15) sums rows 16seg..16seg+15 at k=16bid+kl
      const int kl = t & 15, seg = t >> 4;
      const int k = bid * 16 + kl;
      const double* base = Pp + (size_t)(seg * 16) * KDIM + k;
      double a = 0.0;
#pragma unroll
      for (int j = 0; j < 16; ++j) a += pload(base + (size_t)j * KDIM);
      tmp1[t] = a;                 // ascending b within segment
      __syncthreads();
      if (t < 16) {
        double s = 0.0;
#pragma unroll
        for (int sg = 0; sg < 16; ++sg) s += tmp1[sg * 16 + t];  // ascending
        sfin[t] = s;
      }
      __syncthreads();
      // leg3: replica slice write (thread (rep=seg, kl) -> res[rep][k])
      pstore(Rp + (size_t)seg * KDIM + k, sfin[kl]);
      asm volatile("s_waitcnt vmcnt(0)" ::: "memory");
      __syncthreads();
      if (t == 0) astore(flag2 + bid, ph);
    }
    // leg4: poll the single flag2 line (16 tags), then one-shot row read
    if (t < NREP) {
      unsigned v = aload(flag2 + t);
      while (v < ph) {
        __builtin_amdgcn_s_sleep(1);
        v = aload(flag2 + t);
      }
    }
    __syncthreads();
    return pload(Rp + (size_t)(bid & (NREP - 1)) * KDIM + t);
  };

  auto row_pass = [&](double* dstv) {
    double a0 = alpha[4 * lane + 0], a1 = alpha[4 * lane + 1];
    double a2 = alpha[4 * lane + 2], a3 = alpha[4 * lane + 3];
#pragma unroll 4
    for (int r = wv; r < ROWS; r += 4) {
      float4 e4 = ((const float4*)(Et + r * KDIM))[lane];
      double s1 = a0 * (double)e4.x + a1 * (double)e4.y +
                  a2 * (double)e4.z + a3 * (double)e4.w;
      s1 = wave_sum_d(s1);
      if (lane == 0) dstv[r] = s1;
    }
  };
  auto col_partial = [&]() -> double {
    double a = 0.0;
#pragma unroll 8
    for (int r = 0; r < ROWS; ++r) a += (double)Et[r * KDIM + t] * wrow[r];
    return a;
  };

  // ================= setup =================
  {
    const float4* src = (const float4*)(feat + (size_t)b0 * KDIM);
    float4* dst = (float4*)Ft;
#pragma unroll
    for (int s = 0; s < 16; ++s) dst[s * 256 + t] = src[s * 256 + t];
  }
  __syncthreads();
  for (int r = wv; r < ROWS; r += 4) {
    float4 f4 = ((const float4*)(Ft + r * KDIM))[lane];
    float m = fmaxf(fmaxf(f4.x, f4.y), fmaxf(f4.z, f4.w));
#pragma unroll
    for (int o = 32; o > 0; o >>= 1) m = fmaxf(m, __shfl_down(m, o));
    if (lane == 0) {
      mrow[r] = m;
      sbr[r] = fast_exp_d(20.0 * (double)m);
    }
  }
  __syncthreads();
  double pu0 = 0.0;
#pragma unroll 8
  for (int r = 0; r < ROWS; ++r) {
    float e = exp2f((Ft[r * KDIM + t] - mrow[r]) * L2E20);
    Et[r * KDIM + t] = e;
    pu0 += (double)e * sbr[r];
  }
  float w_t = w_in[t], buf_t = 0.0f;
  double k2_t;
  {
    double x = (double)w_t;
    double m = blk_max(x);
    double e = fast_exp_d(x - m);
    double s = blk_sum(e);
    k2_t = e / s;
  }
  unsigned ph = 1;
  double u0_t = allreduce(ph, pu0);

  // ================= outer loop =================
  for (int it = 0; it < 10; ++it) {
    double u1_t, u2_t;

    // ---- A: v1~, allreduce u1
    alpha[t] = k2_t / u0_t;
    __syncthreads();
    row_pass(v1s);
    __syncthreads();
    if (t < ROWS) wrow[t] = 1.0 / (16384.0 * v1s[t]);
    __syncthreads();
    {
      double pa = col_partial();
      ++ph; u1_t = allreduce(ph, pa);
    }

    // ---- B: v2~, allreduce u2
    alpha[t] = k2_t / u1_t;
    __syncthreads();
    row_pass(v2s);
    __syncthreads();
    if (t < ROWS) wrow[t] = 1.0 / (16384.0 * v2s[t]);
    __syncthreads();
    {
      double pa = col_partial();
      ++ph; u2_t = allreduce(ph, pa);
    }

    if (it == 9) {
      // ---- output: Q[b,k] = alpha3[k]*E~[r,k]/v3~[b]
      alpha[t] = k2_t / u2_t;
      __syncthreads();
      row_pass(v3s);
      __syncthreads();
      if (t < ROWS) wrow[t] = 1.0 / v3s[t];
      __syncthreads();
      double a3 = alpha[t];
#pragma unroll 4
      for (int r = 0; r < ROWS; ++r)
        out[(size_t)(b0 + r) * KDIM + t] =
            (float)(a3 * (double)Et[r * KDIM + t] * wrow[r]);
      return;
    }

    // ---- C: v3~, gv3~; allreduce gsum = (gdir + t3)  [only the sum is used]
    alpha[t] = k2_t / u2_t;
    __syncthreads();
    {
      double a0 = alpha[4 * lane + 0], a1 = alpha[4 * lane + 1];
      double a2 = alpha[4 * lane + 2], a3 = alpha[4 * lane + 3];
#pragma unroll 2
      for (int r = wv; r < ROWS; r += 4) {
        float4 e4 = ((const float4*)(Et + r * KDIM))[lane];
        float4 f4 = ((const float4*)(Ft + r * KDIM))[lane];
        double p0 = a0 * (double)e4.x, p1 = a1 * (double)e4.y;
        double p2 = a2 * (double)e4.z, p3 = a3 * (double)e4.w;
        double s1 = p0 + p1 + p2 + p3;
        double s2 = p0 * (double)f4.x + p1 * (double)f4.y +
                    p2 * (double)f4.z + p3 * (double)f4.w;
        s1 = wave_sum_d(s1);
        s2 = wave_sum_d(s2);
        if (lane == 0) {
          v3s[r] = s1;
          grow[r] = s2 / (16384.0 * s1 * s1);  // gv3~
        }
      }
    }
    __syncthreads();
    if (t < ROWS) wrow[t] = -1.0 / (16384.0 * v3s[t]);
    __syncthreads();
    double gsum_t;
    {
      double ac1 = 0.0, ac2 = 0.0;
#pragma unroll 8
      for (int r = 0; r < ROWS; ++r) {
        double ed = (double)Et[r * KDIM + t];
        ac1 += ed * (double)Ft[r * KDIM + t] * wrow[r];
        ac2 += ed * grow[r];
      }
      ++ph; gsum_t = allreduce(ph, ac1 + ac2);
    }

    // ---- D: gu2 -> gv2~; allreduce ga2
    alpha[t] = -gsum_t * k2_t / (u2_t * u2_t);
    __syncthreads();
    row_pass(grow);
    __syncthreads();
    if (t < ROWS) wrow[t] = -grow[t] / (16384.0 * v2s[t] * v2s[t]);
    __syncthreads();
    double ga2_t;
    {
      double pa = col_partial();
      ++ph; ga2_t = allreduce(ph, pa);
    }

    // ---- E: gu1 -> gv1~; allreduce ga1
    alpha[t] = -ga2_t * k2_t / (u1_t * u1_t);
    __syncthreads();
    row_pass(grow);
    __syncthreads();
    if (t < ROWS) wrow[t] = -grow[t] / (16384.0 * v1s[t] * v1s[t]);
    __syncthreads();
    double ga1_t;
    {
      double pa = col_partial();
      ++ph; ga1_t = allreduce(ph, pa);
    }

    // ---- F: replicated optimizer step (block-local)
    {
      double gk2 = gsum_t / u2_t + ga2_t / u1_t + ga1_t / u0_t;
      double dot = blk_sum(k2_t * gk2);
      double gw = k2_t * (gk2 - dot) + 5.0 * (k2_t / 256.0 - 1.0 / 65536.0);
      double n2 = blk_sum(gw * gw);
      float normf = (float)sqrt(n2);
      float sc = fminf(1.0f, 1.0f / (normf + 1e-6f));
      float g = (float)gw * sc;
      buf_t = 0.99f * buf_t + g;
      w_t = w_t - 0.1f * buf_t;
      double x = (double)w_t;
      double m = blk_max(x);
      double e = fast_exp_d(x - m);
      double s = blk_sum(e);
      k2_t = e / s;
    }
  }
}

// ---------------------------------------------------------------------------
extern "C" void kernel_launch(void* const* d_in, const int* in_sizes, int n_in,
                              void* d_out, int out_size, void* d_ws,
                              size_t ws_size, hipStream_t stream) {
  (void)in_sizes; (void)n_in; (void)out_size; (void)ws_size;
  const float* feat = (const float*)d_in[0];
  const float* w_in = (const float*)d_in[1];
  float* out = (float*)d_out;
  double* ws = (double*)d_ws;

  kInitWS<<<2, 256, 0, stream>>>(ws);
  sink_main<<<NBLK, 256, 0, stream>>>(feat, w_in, out, ws);
}

// Round 9
// 633.220 us; speedup vs baseline: 1.1196x; 1.1196x over previous
//
#include <hip/hip_runtime.h>

// Balanced sinkhorn, persistent kernel, round 14.
// R5-R13: eight store/flag/poll microstructures all land at 9.3-17us per
// allreduce phase — that family's floor is ~9us (R5), ~500us total. Root
// costs: ~6 serial LLC-visibility legs + poll-line serialization.
// R14: hardware far-atomic combine, sharded to dodge R6's per-address
// serialization (R6: 256 same-address fp64 RMWs = 74ns each = 19us; with
// 16 slots the serial depth is 16 => ~1.2us):
//   1. block b: unsafeAtomicAdd(acc[ph][b&15][t], pa)
//      per-phase-fresh slabs acc[48][16][256] (1.5MB, zero reuse/ABA)
//   2. vmcnt(0)+barrier drain (R6-proven) -> t0 fetch_add on SHARDED,
//      LINE-PADDED counter cnt[ph][b&15] (16 blocks/shard, 16 lines)
//   3. threads t<16 poll shard t's line until ==16 (256 pollers/line)
//   4. one-shot coalesced read of 16 slot rows, fixed slot order ->
//      identical total in every block (replicated optimizer consistent)
// Deletes reducer blocks, both flag arrays, replicas, sentinels. fp64 add
// order nondeterministic => ~1e-15 relative noise, invisible at fp32
// output rounding. Phase math / LDS tiles / optimizer identical to R3-R13
// (validated, absmax 2.4e-4).

namespace {

constexpr int KDIM = 256;
constexpr int NBLK = 256;   // 1 block/CU, all co-resident (LDS-forced)
constexpr int ROWS = 64;    // rows per block
constexpr int NSLOT = 16;   // atomic shards per k
constexpr int NPH  = 48;    // 1 + 9*5 + 2 allreduce phases
constexpr float L2E20 = 28.853900817779268f;  // 20 * log2(e)

// ws layout:
//   acc[48 ph][16 slot][256 k]  196608 dbl (1.5 MB), zero-init, per-phase fresh
//   cnt[48 ph][16 shard][16 u32 pad]  12288 u32 (48 KB), zero-init
constexpr size_t ACC_DBL = (size_t)NPH * NSLOT * KDIM;  // 196608
constexpr size_t CNT_OFF_DBL = ACC_DBL;
constexpr int CNT_U32 = NPH * 16 * 16;                  // 12288

__device__ __forceinline__ double fast_exp_d(double x) {
  const double LOG2E  = 1.4426950408889634074;
  const double LN2_HI = 6.93147180369123816490e-01;
  const double LN2_LO = 1.90821492927058770002e-10;
  double n = rint(x * LOG2E);
  double t = fma(-n, LN2_HI, x);
  t = fma(-n, LN2_LO, t);
  double p = 2.4801587301587302e-05;
  p = fma(p, t, 1.9841269841269841e-04);
  p = fma(p, t, 1.3888888888888889e-03);
  p = fma(p, t, 8.3333333333333333e-03);
  p = fma(p, t, 4.1666666666666664e-02);
  p = fma(p, t, 1.6666666666666666e-01);
  p = fma(p, t, 0.5);
  p = fma(p, t, 1.0);
  p = fma(p, t, 1.0);
  long long ni = (long long)n;
  double s = __longlong_as_double((unsigned long long)(ni + 1023LL) << 52);
  return p * s;
}

__device__ __forceinline__ double wave_sum_d(double v) {
#pragma unroll
  for (int o = 32; o > 0; o >>= 1) v += __shfl_down(v, o);
  return v;
}
__device__ __forceinline__ double wave_max_d(double v) {
#pragma unroll
  for (int o = 32; o > 0; o >>= 1) v = fmax(v, __shfl_down(v, o));
  return v;
}

__device__ __forceinline__ double pload(const double* p) {
  return __hip_atomic_load(p, __ATOMIC_RELAXED, __HIP_MEMORY_SCOPE_AGENT);
}
__device__ __forceinline__ unsigned aload(const unsigned* p) {
  return __hip_atomic_load(p, __ATOMIC_RELAXED, __HIP_MEMORY_SCOPE_AGENT);
}

}  // namespace

// ---------------------------------------------------------------------------
__global__ __launch_bounds__(256) void kInitWS(double* __restrict__ ws) {
  size_t gid = (size_t)blockIdx.x * 256 + threadIdx.x;
  size_t stride = (size_t)gridDim.x * 256;
  for (size_t j = gid; j < ACC_DBL; j += stride) ws[j] = 0.0;
  unsigned* c = (unsigned*)(ws + CNT_OFF_DBL);
  for (size_t j = gid; j < (size_t)CNT_U32; j += stride) c[j] = 0u;
}

// ---------------------------------------------------------------------------
__global__ __launch_bounds__(256, 1) void sink_main(
    const float* __restrict__ feat, const float* __restrict__ w_in,
    float* __restrict__ out, double* __restrict__ ws) {
  __shared__ float  Et[ROWS * KDIM];   // 64 KB
  __shared__ float  Ft[ROWS * KDIM];   // 64 KB
  __shared__ double alpha[KDIM];
  __shared__ double v1s[ROWS], v2s[ROWS], v3s[ROWS];
  __shared__ double grow[ROWS], wrow[ROWS], sbr[ROWS];
  __shared__ float  mrow[ROWS];
  __shared__ double sred[8];

  const int t = threadIdx.x, bid = blockIdx.x;
  const int wv = t >> 6, lane = t & 63;
  const int b0 = bid * ROWS;
  const int slot = bid & (NSLOT - 1);

  double* acc = ws;
  unsigned* cnt = (unsigned*)(ws + CNT_OFF_DBL);

  auto blk_sum = [&](double v) -> double {
    v = wave_sum_d(v);
    __syncthreads();
    if (lane == 0) sred[wv] = v;
    __syncthreads();
    return sred[0] + sred[1] + sred[2] + sred[3];
  };
  auto blk_max = [&](double v) -> double {
    v = wave_max_d(v);
    __syncthreads();
    if (lane == 0) sred[wv + 4] = v;
    __syncthreads();
    return fmax(fmax(sred[4], sred[5]), fmax(sred[6], sred[7]));
  };

  // ---- allreduce over blocks: thread t contributes pa for k=t,
  // returns the 256-block sum for k=t (identical in every block).
  auto allreduce = [&](unsigned ph, double pa) -> double {
    double* A = acc + (size_t)ph * NSLOT * KDIM;
    // 1. sharded far-atomic combine (per-address depth 16)
    unsafeAtomicAdd(A + (size_t)slot * KDIM + t, pa);
    asm volatile("s_waitcnt vmcnt(0)" ::: "memory");
    __syncthreads();  // block's RMWs ack'd at the coherence point
    // 2. sharded arrival counter (line-padded: 16 shards x 64B)
    if (t == 0)
      __hip_atomic_fetch_add(cnt + ((size_t)ph * 16 + slot) * 16, 1u,
                             __ATOMIC_RELAXED, __HIP_MEMORY_SCOPE_AGENT);
    // 3. detect: thread t<16 polls shard t's line until ==16
    if (t < NSLOT) {
      const unsigned* c = cnt + ((size_t)ph * 16 + t) * 16;
      unsigned v = aload(c);
      while (v < 16u) {
        __builtin_amdgcn_s_sleep(4);
        v = aload(c);
      }
    }
    __syncthreads();
    // 4. one-shot coalesced read, fixed slot order (deterministic per run)
    const double* A0 = A + t;
    double tot = 0.0;
#pragma unroll
    for (int s = 0; s < NSLOT; ++s) tot += pload(A0 + (size_t)s * KDIM);
    return tot;
  };

  auto row_pass = [&](double* dstv) {
    double a0 = alpha[4 * lane + 0], a1 = alpha[4 * lane + 1];
    double a2 = alpha[4 * lane + 2], a3 = alpha[4 * lane + 3];
#pragma unroll 4
    for (int r = wv; r < ROWS; r += 4) {
      float4 e4 = ((const float4*)(Et + r * KDIM))[lane];
      double s1 = a0 * (double)e4.x + a1 * (double)e4.y +
                  a2 * (double)e4.z + a3 * (double)e4.w;
      s1 = wave_sum_d(s1);
      if (lane == 0) dstv[r] = s1;
    }
  };
  auto col_partial = [&]() -> double {
    double a = 0.0;
#pragma unroll 8
    for (int r = 0; r < ROWS; ++r) a += (double)Et[r * KDIM + t] * wrow[r];
    return a;
  };

  // ================= setup =================
  {
    const float4* src = (const float4*)(feat + (size_t)b0 * KDIM);
    float4* dst = (float4*)Ft;
#pragma unroll
    for (int s = 0; s < 16; ++s) dst[s * 256 + t] = src[s * 256 + t];
  }
  __syncthreads();
  for (int r = wv; r < ROWS; r += 4) {
    float4 f4 = ((const float4*)(Ft + r * KDIM))[lane];
    float m = fmaxf(fmaxf(f4.x, f4.y), fmaxf(f4.z, f4.w));
#pragma unroll
    for (int o = 32; o > 0; o >>= 1) m = fmaxf(m, __shfl_down(m, o));
    if (lane == 0) {
      mrow[r] = m;
      sbr[r] = fast_exp_d(20.0 * (double)m);
    }
  }
  __syncthreads();
  double pu0 = 0.0;
#pragma unroll 8
  for (int r = 0; r < ROWS; ++r) {
    float e = exp2f((Ft[r * KDIM + t] - mrow[r]) * L2E20);
    Et[r * KDIM + t] = e;
    pu0 += (double)e * sbr[r];
  }
  float w_t = w_in[t], buf_t = 0.0f;
  double k2_t;
  {
    double x = (double)w_t;
    double m = blk_max(x);
    double e = fast_exp_d(x - m);
    double s = blk_sum(e);
    k2_t = e / s;
  }
  unsigned ph = 0;
  double u0_t = allreduce(ph, pu0);

  // ================= outer loop =================
  for (int it = 0; it < 10; ++it) {
    double u1_t, u2_t;

    // ---- A: v1~, allreduce u1
    alpha[t] = k2_t / u0_t;
    __syncthreads();
    row_pass(v1s);
    __syncthreads();
    if (t < ROWS) wrow[t] = 1.0 / (16384.0 * v1s[t]);
    __syncthreads();
    {
      double pa = col_partial();
      ++ph; u1_t = allreduce(ph, pa);
    }

    // ---- B: v2~, allreduce u2
    alpha[t] = k2_t / u1_t;
    __syncthreads();
    row_pass(v2s);
    __syncthreads();
    if (t < ROWS) wrow[t] = 1.0 / (16384.0 * v2s[t]);
    __syncthreads();
    {
      double pa = col_partial();
      ++ph; u2_t = allreduce(ph, pa);
    }

    if (it == 9) {
      // ---- output: Q[b,k] = alpha3[k]*E~[r,k]/v3~[b]
      alpha[t] = k2_t / u2_t;
      __syncthreads();
      row_pass(v3s);
      __syncthreads();
      if (t < ROWS) wrow[t] = 1.0 / v3s[t];
      __syncthreads();
      double a3 = alpha[t];
#pragma unroll 4
      for (int r = 0; r < ROWS; ++r)
        out[(size_t)(b0 + r) * KDIM + t] =
            (float)(a3 * (double)Et[r * KDIM + t] * wrow[r]);
      return;
    }

    // ---- C: v3~, gv3~; allreduce gsum = (gdir + t3)  [only the sum is used]
    alpha[t] = k2_t / u2_t;
    __syncthreads();
    {
      double a0 = alpha[4 * lane + 0], a1 = alpha[4 * lane + 1];
      double a2 = alpha[4 * lane + 2], a3 = alpha[4 * lane + 3];
#pragma unroll 2
      for (int r = wv; r < ROWS; r += 4) {
        float4 e4 = ((const float4*)(Et + r * KDIM))[lane];
        float4 f4 = ((const float4*)(Ft + r * KDIM))[lane];
        double p0 = a0 * (double)e4.x, p1 = a1 * (double)e4.y;
        double p2 = a2 * (double)e4.z, p3 = a3 * (double)e4.w;
        double s1 = p0 + p1 + p2 + p3;
        double s2 = p0 * (double)f4.x + p1 * (double)f4.y +
                    p2 * (double)f4.z + p3 * (double)f4.w;
        s1 = wave_sum_d(s1);
        s2 = wave_sum_d(s2);
        if (lane == 0) {
          v3s[r] = s1;
          grow[r] = s2 / (16384.0 * s1 * s1);  // gv3~
        }
      }
    }
    __syncthreads();
    if (t < ROWS) wrow[t] = -1.0 / (16384.0 * v3s[t]);
    __syncthreads();
    double gsum_t;
    {
      double ac1 = 0.0, ac2 = 0.0;
#pragma unroll 8
      for (int r = 0; r < ROWS; ++r) {
        double ed = (double)Et[r * KDIM + t];
        ac1 += ed * (double)Ft[r * KDIM + t] * wrow[r];
        ac2 += ed * grow[r];
      }
      ++ph; gsum_t = allreduce(ph, ac1 + ac2);
    }

    // ---- D: gu2 -> gv2~; allreduce ga2
    alpha[t] = -gsum_t * k2_t / (u2_t * u2_t);
    __syncthreads();
    row_pass(grow);
    __syncthreads();
    if (t < ROWS) wrow[t] = -grow[t] / (16384.0 * v2s[t] * v2s[t]);
    __syncthreads();
    double ga2_t;
    {
      double pa = col_partial();
      ++ph; ga2_t = allreduce(ph, pa);
    }

    // ---- E: gu1 -> gv1~; allreduce ga1
    alpha[t] = -ga2_t * k2_t / (u1_t * u1_t);
    __syncthreads();
    row_pass(grow);
    __syncthreads();
    if (t < ROWS) wrow[t] = -grow[t] / (16384.0 * v1s[t] * v1s[t]);
    __syncthreads();
    double ga1_t;
    {
      double pa = col_partial();
      ++ph; ga1_t = allreduce(ph, pa);
    }

    // ---- F: replicated optimizer step (block-local)
    {
      double gk2 = gsum_t / u2_t + ga2_t / u1_t + ga1_t / u0_t;
      double dot = blk_sum(k2_t * gk2);
      double gw = k2_t * (gk2 - dot) + 5.0 * (k2_t / 256.0 - 1.0 / 65536.0);
      double n2 = blk_sum(gw * gw);
      float normf = (float)sqrt(n2);
      float sc = fminf(1.0f, 1.0f / (normf + 1e-6f));
      float g = (float)gw * sc;
      buf_t = 0.99f * buf_t + g;
      w_t = w_t - 0.1f * buf_t;
      double x = (double)w_t;
      double m = blk_max(x);
      double e = fast_exp_d(x - m);
      double s = blk_sum(e);
      k2_t = e / s;
    }
  }
}

// ---------------------------------------------------------------------------
extern "C" void kernel_launch(void* const* d_in, const int* in_sizes, int n_in,
                              void* d_out, int out_size, void* d_ws,
                              size_t ws_size, hipStream_t stream) {
  (void)in_sizes; (void)n_in; (void)out_size; (void)ws_size;
  const float* feat = (const float*)d_in[0];
  const float* w_in = (const float*)d_in[1];
  float* out = (float*)d_out;
  double* ws = (double*)d_ws;

  kInitWS<<<128, 256, 0, stream>>>(ws);
  sink_main<<<NBLK, 256, 0, stream>>>(feat, w_in, out, ws);
}